// Round 12
// baseline (184.956 us; speedup 1.0000x reference)
//
#include <hip/hip_runtime.h>
#include <cstdint>
#include <cstddef>

using f32x4  = __attribute__((ext_vector_type(4))) float;
using bf16x8 = __attribute__((ext_vector_type(8))) short;

__device__ __forceinline__ unsigned short f2bf(float f){
  unsigned int u = __float_as_uint(f);
  return (unsigned short)((u + 0x7fffu + ((u >> 16) & 1u)) >> 16);
}

// swizzles: XOR 16B-slot bits with row&7 (row = 512B or 128B)
#define SWZ(o)    ((o) ^ ((((o) >> 9) & 7) << 4))
#define SWZ128(o) ((o) ^ ((((o) >> 7) & 7) << 4))

// ---------------------------------------------------------------------------
// Prologue: PWt pack (k/v weights in MFMA B-frag order) + zero Uacc/Sacc.
__global__ __launch_bounds__(256) void k_prep(
    const float* __restrict__ Wk, const float* __restrict__ Wv,
    unsigned short* __restrict__ PWt, float* __restrict__ Uacc /* + Sacc tail */){
  const int bx = blockIdx.x, t = threadIdx.x;
  int idx = bx * 256 + t;                   // 32768 total
  int e = idx & 7, lane = (idx >> 3) & 63, f = idx >> 9;
  int pass = f >> 5, brT = (f >> 3) & 3, kk = f & 7;
  int n_loc = brT * 16 + (lane & 15);
  int c = kk * 32 + (lane >> 4) * 8 + e;
  const float* src = pass ? Wv : Wk;
  PWt[idx] = f2bf(src[c * 64 + n_loc]);
  #pragma unroll
  for (int i = 0; i < 3; ++i){
    int z = idx + 32768 * i;
    if (z < 83200) Uacc[z] = 0.f;           // Uacc (81920) + Sacc (1280)
  }
}

// ---------------------------------------------------------------------------
// Fused LN + (x@Wk | x@Wv), BM=32. Outputs in MFMA B-fragment order.
// Extra blocks (>=8192): slot-weight packing (240) and slot init+q (320),
// overlapped with the memory-bound main read.
__global__ __launch_bounds__(256) void k_lnkv(
    const float* __restrict__ x, const float* __restrict__ lng, const float* __restrict__ lnb,
    const unsigned short* __restrict__ PWt,
    unsigned short* __restrict__ kbF, unsigned short* __restrict__ vF,
    const float* __restrict__ Wih, const float* __restrict__ Whh,
    const float* __restrict__ W1,  const float* __restrict__ W2,
    const float* __restrict__ Wq,
    const float* __restrict__ noise, const float* __restrict__ mu,
    const float* __restrict__ lsig,
    const float* __restrict__ lsg, const float* __restrict__ lsb,
    unsigned short* __restrict__ PWih, unsigned short* __restrict__ PWhh,
    unsigned short* __restrict__ PW1T, unsigned short* __restrict__ PW2T,
    unsigned short* __restrict__ PWq,
    float* __restrict__ slots, float* __restrict__ qws){
  extern __shared__ char smem[];
  const int t = threadIdx.x;
  const int bx = blockIdx.x;

  if (bx >= 8192){
    if (bx < 8432){
      // slot-path weight packing (moved from k_prep)
      int idx = (bx - 8192) * 256 + t;   // 61440 total
      int rel, kstN;
      const float* src; unsigned short* dst; int mode;
      if (idx < 12288)      { rel = idx;          kstN = 2; src = Wih; dst = PWih; mode = 0; }
      else if (idx < 24576) { rel = idx - 12288;  kstN = 2; src = Whh; dst = PWhh; mode = 0; }
      else if (idx < 40960) { rel = idx - 24576;  kstN = 2; src = W1;  dst = PW1T; mode = 1; }
      else if (idx < 57344) { rel = idx - 40960;  kstN = 8; src = W2;  dst = PW2T; mode = 2; }
      else                  { rel = idx - 57344;  kstN = 2; src = Wq;  dst = PWq;  mode = 3; }
      int e = rel & 7, lane = (rel >> 3) & 63, f = rel >> 9;
      int jt = f / kstN, kst = f - jt * kstN;
      int row = jt * 16 + (lane & 15);
      int col = kst * 32 + (lane >> 4) * 8 + e;
      float v;
      if (mode == 0)      v = src[row * 64 + col];
      else if (mode == 1) v = src[col * 256 + row];
      else if (mode == 2) v = src[col * 64 + row];
      else                v = src[col * 64 + row];
      dst[rel] = f2bf(v);
      return;
    }
    // slot init + initial q
    {
      float* xsh = (float*)smem;          // [4][64]
      int idx = bx - 8432;
      int d = t & 63, w4 = t >> 6;
      int bk = idx * 4 + w4;
      float s = mu[d] + __expf(lsig[d]) * noise[bk * 64 + d];
      slots[bk * 64 + d] = s;
      float s1 = s, s2 = s * s;
      #pragma unroll
      for (int off = 32; off >= 1; off >>= 1){
        s1 += __shfl_xor(s1, off);
        s2 += __shfl_xor(s2, off);
      }
      float m = s1 * (1.f / 64.f);
      float var = s2 * (1.f / 64.f) - m * m;
      float rstd = rsqrtf(var + 1e-5f);
      float xn = (s - m) * rstd * lsg[d] + lsb[d];
      xsh[w4 * 64 + d] = xn;
      __syncthreads();
      float q = 0.f;
      #pragma unroll
      for (int i = 0; i < 64; ++i) q += xsh[w4 * 64 + i] * Wq[i * 64 + d];
      qws[bk * 64 + d] = q;
      return;
    }
  }

  char* As = smem;            // 32 x 256 bf16, swizzled (16KB)
  char* Cs = smem + 16384;    // 32 x 64 bf16 output staging (4KB)
  const int lane = t & 63, w = t >> 6;
  const int gm0 = bx * 32;

  const float4 g4 = *(const float4*)(lng + lane * 4);
  const float4 b4 = *(const float4*)(lnb + lane * 4);

  {
    float4 xv[8];
    #pragma unroll
    for (int j = 0; j < 8; ++j){
      int r = w * 8 + j;
      xv[j] = *(const float4*)(x + (size_t)(gm0 + r) * 256 + lane * 4);
    }
    #pragma unroll
    for (int j = 0; j < 8; ++j){
      int r = w * 8 + j;
      float4 v = xv[j];
      float s  = v.x + v.y + v.z + v.w;
      float s2 = v.x * v.x + v.y * v.y + v.z * v.z + v.w * v.w;
      #pragma unroll
      for (int off = 32; off >= 1; off >>= 1){
        s  += __shfl_xor(s,  off);
        s2 += __shfl_xor(s2, off);
      }
      float mean = s * (1.f / 256.f);
      float var  = s2 * (1.f / 256.f) - mean * mean;
      float rstd = rsqrtf(var + 1e-5f);
      unsigned int p0 = (unsigned)f2bf((v.x - mean) * rstd * g4.x + b4.x) |
                        ((unsigned)f2bf((v.y - mean) * rstd * g4.y + b4.y) << 16);
      unsigned int p1 = (unsigned)f2bf((v.z - mean) * rstd * g4.z + b4.z) |
                        ((unsigned)f2bf((v.w - mean) * rstd * g4.w + b4.w) << 16);
      int off8 = r * 512 + lane * 8;
      *(uint2*)(As + SWZ(off8)) = make_uint2(p0, p1);
    }
  }
  __syncthreads();

  const int wm = w >> 1, wn = w & 1;
  const int l15 = lane & 15, l4 = lane >> 4;

  #pragma unroll 1
  for (int pass = 0; pass < 2; ++pass){
    f32x4 acc[2];
    acc[0] = (f32x4){0.f,0.f,0.f,0.f};
    acc[1] = (f32x4){0.f,0.f,0.f,0.f};

    #pragma unroll
    for (int kk = 0; kk < 8; ++kk){
      int ar = wm * 16 + l15;
      bf16x8 a = *(const bf16x8*)(As + SWZ(ar * 512 + kk * 64 + l4 * 16));
      bf16x8 bfr[2];
      #pragma unroll
      for (int j = 0; j < 2; ++j){
        int f = pass * 32 + (wn * 2 + j) * 8 + kk;
        bfr[j] = *(const bf16x8*)(PWt + ((size_t)(f * 64 + lane)) * 8);
      }
      #pragma unroll
      for (int j = 0; j < 2; ++j)
        acc[j] = __builtin_amdgcn_mfma_f32_16x16x32_bf16(a, bfr[j], acc[j], 0, 0, 0);
    }
    if (pass == 1) __syncthreads();

    #pragma unroll
    for (int j = 0; j < 2; ++j)
      #pragma unroll
      for (int reg = 0; reg < 4; ++reg){
        int row = wm * 16 + l4 * 4 + reg;
        int colb = ((wn * 2 + j) * 16 + l15) * 2;
        *(unsigned short*)(Cs + row * 128 + (colb ^ ((row & 7) << 4))) = f2bf(acc[j][reg]);
      }
    __syncthreads();

    if (pass == 0){
      const int lo = t & 63, kst = (t >> 6) & 1, nt = t >> 7;
      int row = nt * 16 + (lo & 15);
      int colb = (kst * 32 + (lo >> 4) * 8) * 2;
      uint4 val = *(const uint4*)(Cs + row * 128 + (colb ^ ((row & 7) << 4)));
      size_t ntile = (size_t)bx * 2 + nt;
      *(uint4*)(kbF + (ntile * 2 + kst) * 512 + lo * 8) = val;
    } else {
      const size_t chunkF = (size_t)(gm0 >> 7);
      const int kstG = (gm0 >> 5) & 3;
      const int dtile = t >> 6;
      unsigned short ev[8];
      #pragma unroll
      for (int e = 0; e < 8; ++e){
        int row = (lane >> 4) * 8 + e;
        int colb = (dtile * 16 + (lane & 15)) * 2;
        ev[e] = *(const unsigned short*)(Cs + row * 128 + (colb ^ ((row & 7) << 4)));
      }
      *(uint4*)(vF + ((chunkF * 4 + dtile) * 4 + kstG) * 512 + lane * 8) = *(const uint4*)ev;
    }
  }
}

// ---------------------------------------------------------------------------
// MFMA attention, fragment-direct; partial sums via atomicAdd into Uacc/Sacc.
__global__ __launch_bounds__(256) void k_attn2(
    const unsigned short* __restrict__ kbF, const unsigned short* __restrict__ vF,
    const float* __restrict__ qws, float* __restrict__ Sacc, float* __restrict__ Uacc,
    float* __restrict__ attn_out, int write_attn){
  __shared__ __align__(16) char sm[12672];
  char* qs  = sm;                       // [32][64] bf16 swz (4KB)
  char* Ps  = sm + 4096;                // [32][128] bf16 swz (8KB)
  float* sred = (float*)(sm + 12288);   // [20][4]
  const int t = threadIdx.x, lane = t & 63, w = t >> 6;
  const int l15 = lane & 15, g = lane >> 4;
  const int b = blockIdx.y, chunk = blockIdx.x, n0 = chunk * 128;

  if (t < 160){
    int r = t >> 3, c = t & 7;
    const float4* qp = (const float4*)(qws + (size_t)b * 1280 + r * 64 + c * 8);
    float4 a0 = qp[0], a1 = qp[1];
    uint4 pk;
    pk.x = (unsigned)f2bf(a0.x) | ((unsigned)f2bf(a0.y) << 16);
    pk.y = (unsigned)f2bf(a0.z) | ((unsigned)f2bf(a0.w) << 16);
    pk.z = (unsigned)f2bf(a1.x) | ((unsigned)f2bf(a1.y) << 16);
    pk.w = (unsigned)f2bf(a1.z) | ((unsigned)f2bf(a1.w) << 16);
    *(uint4*)(qs + r * 128 + ((c * 16) ^ ((r & 7) << 4))) = pk;
  }
  __syncthreads();

  f32x4 c2[2][2];
  #pragma unroll
  for (int kt = 0; kt < 2; ++kt)
    #pragma unroll
    for (int nt = 0; nt < 2; ++nt)
      c2[kt][nt] = (f32x4){0.f, 0.f, 0.f, 0.f};
  #pragma unroll
  for (int kst = 0; kst < 2; ++kst){
    bf16x8 aq[2], bk2[2];
    #pragma unroll
    for (int kt = 0; kt < 2; ++kt){
      int row = kt * 16 + l15;
      aq[kt] = *(const bf16x8*)(qs + row * 128 + ((kst * 64 + g * 16) ^ ((row & 7) << 4)));
    }
    #pragma unroll
    for (int nt = 0; nt < 2; ++nt){
      size_t ntile = (size_t)b * 256 + chunk * 8 + w * 2 + nt;
      bk2[nt] = *(const bf16x8*)(kbF + (ntile * 2 + kst) * 512 + lane * 8);
    }
    #pragma unroll
    for (int kt = 0; kt < 2; ++kt)
      #pragma unroll
      for (int nt = 0; nt < 2; ++nt)
        c2[kt][nt] = __builtin_amdgcn_mfma_f32_16x16x32_bf16(aq[kt], bk2[nt], c2[kt][nt], 0, 0, 0);
  }

  float p[2][2][4];
  #pragma unroll
  for (int kt = 0; kt < 2; ++kt)
    #pragma unroll
    for (int nt = 0; nt < 2; ++nt)
      #pragma unroll
      for (int reg = 0; reg < 4; ++reg)
        p[kt][nt][reg] = c2[kt][nt][reg] * 0.125f;
  if (g){
    #pragma unroll
    for (int nt = 0; nt < 2; ++nt)
      #pragma unroll
      for (int reg = 0; reg < 4; ++reg)
        p[1][nt][reg] = -1e30f;
  }

  #pragma unroll
  for (int nt = 0; nt < 2; ++nt){
    float mx = p[0][nt][0];
    #pragma unroll
    for (int reg = 1; reg < 4; ++reg) mx = fmaxf(mx, p[0][nt][reg]);
    #pragma unroll
    for (int reg = 0; reg < 4; ++reg) mx = fmaxf(mx, p[1][nt][reg]);
    mx = fmaxf(mx, __shfl_xor(mx, 16));
    mx = fmaxf(mx, __shfl_xor(mx, 32));
    float s = 0.f;
    #pragma unroll
    for (int kt = 0; kt < 2; ++kt)
      #pragma unroll
      for (int reg = 0; reg < 4; ++reg){
        float e = __expf(p[kt][nt][reg] - mx);
        p[kt][nt][reg] = e; s += e;
      }
    s += __shfl_xor(s, 16);
    s += __shfl_xor(s, 32);
    float inv = 1.f / s;
    #pragma unroll
    for (int kt = 0; kt < 2; ++kt)
      #pragma unroll
      for (int reg = 0; reg < 4; ++reg)
        p[kt][nt][reg] *= inv;
  }

  {
    float sr[2][4];
    #pragma unroll
    for (int kt = 0; kt < 2; ++kt)
      #pragma unroll
      for (int reg = 0; reg < 4; ++reg)
        sr[kt][reg] = p[kt][0][reg] + p[kt][1][reg];
    #pragma unroll
    for (int off = 1; off <= 8; off <<= 1)
      #pragma unroll
      for (int kt = 0; kt < 2; ++kt)
        #pragma unroll
        for (int reg = 0; reg < 4; ++reg)
          sr[kt][reg] += __shfl_xor(sr[kt][reg], off);
    if (l15 == 0){
      #pragma unroll
      for (int kt = 0; kt < 2; ++kt)
        #pragma unroll
        for (int reg = 0; reg < 4; ++reg){
          int ks = kt * 16 + g * 4 + reg;
          if (ks < 20) sred[ks * 4 + w] = sr[kt][reg];
        }
    }
  }

  if (write_attn){
    #pragma unroll
    for (int kt = 0; kt < 2; ++kt)
      #pragma unroll
      for (int nt = 0; nt < 2; ++nt)
        #pragma unroll
        for (int reg = 0; reg < 4; ++reg){
          int ks = kt * 16 + g * 4 + reg;
          if (ks < 20)
            attn_out[((size_t)(b * 20 + ks)) * 4096 + n0 + w * 32 + nt * 16 + l15] = p[kt][nt][reg];
        }
  }

  #pragma unroll
  for (int kt = 0; kt < 2; ++kt)
    #pragma unroll
    for (int nt = 0; nt < 2; ++nt)
      #pragma unroll
      for (int reg = 0; reg < 4; ++reg){
        int row = kt * 16 + g * 4 + reg;
        int colb = (w * 32 + nt * 16 + l15) * 2;
        *(unsigned short*)(Ps + row * 256 + (colb ^ ((row & 7) << 4))) = f2bf(p[kt][nt][reg]);
      }
  __syncthreads();

  if (t < 20)
    atomicAdd(Sacc + (size_t)b * 20 + t,
              sred[t * 4 + 0] + sred[t * 4 + 1] + sred[t * 4 + 2] + sred[t * 4 + 3]);

  f32x4 u[2];
  u[0] = (f32x4){0.f,0.f,0.f,0.f};
  u[1] = (f32x4){0.f,0.f,0.f,0.f};
  #pragma unroll
  for (int kst = 0; kst < 4; ++kst){
    bf16x8 pa[2], bv;
    #pragma unroll
    for (int kt = 0; kt < 2; ++kt){
      int row = kt * 16 + l15;
      pa[kt] = *(const bf16x8*)(Ps + row * 256 + ((kst * 64 + g * 16) ^ ((row & 7) << 4)));
    }
    bv = *(const bf16x8*)(vF + ((((size_t)b * 32 + chunk) * 4 + w) * 4 + kst) * 512 + lane * 8);
    #pragma unroll
    for (int kt = 0; kt < 2; ++kt)
      u[kt] = __builtin_amdgcn_mfma_f32_16x16x32_bf16(pa[kt], bv, u[kt], 0, 0, 0);
  }
  #pragma unroll
  for (int kt = 0; kt < 2; ++kt)
    #pragma unroll
    for (int reg = 0; reg < 4; ++reg){
      int ks = kt * 16 + g * 4 + reg;
      if (ks < 20)
        atomicAdd(Uacc + (size_t)b * 1280 + ks * 64 + w * 16 + l15, u[kt][reg]);
    }
}

// ---------------------------------------------------------------------------
// Fused slot update, 1024 threads. Reads Uacc/Sacc and self-zeroes them
// (each thread zeroes the address it read) for the next dispatch.
__global__ __launch_bounds__(1024) void k_slot(
    float* __restrict__ slots, float* __restrict__ Uacc, float* __restrict__ Sacc,
    const unsigned short* __restrict__ PWih, const unsigned short* __restrict__ PWhh,
    const unsigned short* __restrict__ PW1T, const unsigned short* __restrict__ PW2T,
    const unsigned short* __restrict__ PWq,
    const float* __restrict__ bih, const float* __restrict__ bhh,
    const float* __restrict__ b1, const float* __restrict__ b2,
    const float* __restrict__ lmg, const float* __restrict__ lmb,
    const float* __restrict__ lsg, const float* __restrict__ lsb,
    float* __restrict__ qws, float* __restrict__ out_slots, int last){
  extern __shared__ char sm[];
  float* g1f = (float*)sm;                 // [192][33] f32 (25,344B)
  float* g2f = g1f + 192 * 33;             // [192][33] f32
  char*  reluT = sm;                       // [32][256] bf16 swz512 (16KB) -- aliases g1f/g2f
  char*  ubf   = sm + 50688;               // [32][64] bf16 swz128 (4KB)
  char*  sbfb  = sm + 54784;
  char*  hbf   = sm + 58880;
  char*  sqbf  = sm + 62976;
  float* snewF = (float*)(sm + 67072);     // [32][65] f32
  float* prevF = (float*)(sm + 75392);
  float* sfinF = (float*)(sm + 83712);
  float* sSr   = (float*)(sm + 92032);     // [20] f32  (total 92,160B)

  const int t = threadIdx.x, lane = t & 63, wv = t >> 6;
  const int l15 = lane & 15, g4 = lane >> 4;
  const int b = blockIdx.x;

  // phase 0a: S read + self-zero
  if (t < 20){
    float ss = Sacc[(size_t)b * 20 + t];
    Sacc[(size_t)b * 20 + t] = 0.f;
    sSr[t] = 1.f / (ss + 1e-8f);
  }
  __syncthreads();

  // phase 0b: U read + self-zero + stage updates/prev
  #pragma unroll
  for (int i = 0; i < 2; ++i){
    int idx = t + 1024 * i;
    if (idx < 1280){
      int m = idx >> 6, d = idx & 63;
      float uv = Uacc[(size_t)b * 1280 + idx];
      Uacc[(size_t)b * 1280 + idx] = 0.f;
      uv *= sSr[m];
      float pv = slots[((size_t)b * 20 + m) * 64 + d];
      int off = m * 128 + d * 2;
      *(unsigned short*)(ubf  + SWZ128(off)) = f2bf(uv);
      *(unsigned short*)(sbfb + SWZ128(off)) = f2bf(pv);
      prevF[m * 65 + d] = pv;
    }
  }
  __syncthreads();

  // phase 1: gate GEMMs
  {
    const int which = wv >> 3, mg = (wv >> 2) & 1, jg = wv & 3;
    const unsigned short* PA = which ? PWhh : PWih;
    const char* Bt = which ? sbfb : ubf;
    float* gout = which ? g2f : g1f;
    f32x4 acc[3];
    #pragma unroll
    for (int jj = 0; jj < 3; ++jj) acc[jj] = (f32x4){0.f,0.f,0.f,0.f};
    #pragma unroll
    for (int kst = 0; kst < 2; ++kst){
      int roff = (mg * 16 + l15) * 128 + (kst * 32 + g4 * 8) * 2;
      bf16x8 bfrag = *(const bf16x8*)(Bt + SWZ128(roff));
      #pragma unroll
      for (int jj = 0; jj < 3; ++jj){
        int jt = jg * 3 + jj;
        bf16x8 afrag = *(const bf16x8*)(PA + ((size_t)((jt * 2 + kst) * 64 + lane)) * 8);
        acc[jj] = __builtin_amdgcn_mfma_f32_16x16x32_bf16(afrag, bfrag, acc[jj], 0, 0, 0);
      }
    }
    #pragma unroll
    for (int jj = 0; jj < 3; ++jj){
      int jt = jg * 3 + jj;
      #pragma unroll
      for (int reg = 0; reg < 4; ++reg)
        gout[(jt * 16 + g4 * 4 + reg) * 33 + mg * 16 + l15] = acc[jj][reg];
    }
  }
  __syncthreads();

  // phase 2: gate combine + GRU + LN(mlp) -> hbf
  {
    const int d = lane;
    const float bi_r = bih[d], bi_z = bih[64 + d], bi_n = bih[128 + d];
    const float bh_r = bhh[d], bh_z = bhh[64 + d], bh_n = bhh[128 + d];
    const float lg = lmg[d], lb = lmb[d];
    #pragma unroll
    for (int mi = 0; mi < 2; ++mi){
      int m = wv + mi * 16;
      if (m < 20){
        float i_r = g1f[d * 33 + m] + bi_r;
        float i_z = g1f[(64 + d) * 33 + m] + bi_z;
        float i_n = g1f[(128 + d) * 33 + m] + bi_n;
        float h_r = g2f[d * 33 + m] + bh_r;
        float h_z = g2f[(64 + d) * 33 + m] + bh_z;
        float h_n = g2f[(128 + d) * 33 + m] + bh_n;
        float r = 1.f / (1.f + __expf(-(i_r + h_r)));
        float z = 1.f / (1.f + __expf(-(i_z + h_z)));
        float nn = tanhf(i_n + r * h_n);
        float pv = prevF[m * 65 + d];
        float sn = (1.f - z) * nn + z * pv;
        snewF[m * 65 + d] = sn;
        float s1 = sn, s2 = sn * sn;
        #pragma unroll
        for (int off = 32; off >= 1; off >>= 1){
          s1 += __shfl_xor(s1, off);
          s2 += __shfl_xor(s2, off);
        }
        float mean = s1 * (1.f / 64.f);
        float var = s2 * (1.f / 64.f) - mean * mean;
        float rstd = rsqrtf(var + 1e-5f);
        float h = (sn - mean) * rstd * lg + lb;
        *(unsigned short*)(hbf + SWZ128(m * 128 + d * 2)) = f2bf(h);
      }
    }
  }
  __syncthreads();

  // phase 3: relu(h@W1+b1) -> reluT
  {
    const int jt = wv;
    f32x4 acc[2];
    acc[0] = (f32x4){0.f,0.f,0.f,0.f};
    acc[1] = (f32x4){0.f,0.f,0.f,0.f};
    #pragma unroll
    for (int kst = 0; kst < 2; ++kst){
      bf16x8 afrag = *(const bf16x8*)(PW1T + ((size_t)((jt * 2 + kst) * 64 + lane)) * 8);
      #pragma unroll
      for (int mg = 0; mg < 2; ++mg){
        int roff = (mg * 16 + l15) * 128 + (kst * 32 + g4 * 8) * 2;
        bf16x8 bh2 = *(const bf16x8*)(hbf + SWZ128(roff));
        acc[mg] = __builtin_amdgcn_mfma_f32_16x16x32_bf16(afrag, bh2, acc[mg], 0, 0, 0);
      }
    }
    #pragma unroll
    for (int reg = 0; reg < 4; ++reg){
      int j = jt * 16 + g4 * 4 + reg;
      float bb = b1[j];
      #pragma unroll
      for (int mg = 0; mg < 2; ++mg){
        float vv = fmaxf(acc[mg][reg] + bb, 0.f);
        int m = mg * 16 + l15;
        int off = m * 512 + j * 2;
        *(unsigned short*)(reluT + SWZ(off)) = f2bf(vv);
      }
    }
  }
  __syncthreads();

  // phase 4: relu@W2 + b2 + snew -> slots
  if (wv < 8){
    const int dd = wv >> 1, mg = wv & 1;
    f32x4 acc = (f32x4){0.f,0.f,0.f,0.f};
    #pragma unroll
    for (int kst = 0; kst < 8; ++kst){
      bf16x8 afrag = *(const bf16x8*)(PW2T + ((size_t)((dd * 8 + kst) * 64 + lane)) * 8);
      int row = mg * 16 + l15;
      int off = row * 512 + (kst * 32 + g4 * 8) * 2;
      bf16x8 bfrag = *(const bf16x8*)(reluT + SWZ(off));
      acc = __builtin_amdgcn_mfma_f32_16x16x32_bf16(afrag, bfrag, acc, 0, 0, 0);
    }
    #pragma unroll
    for (int reg = 0; reg < 4; ++reg){
      int m = mg * 16 + l15;
      int dcol = dd * 16 + g4 * 4 + reg;
      if (m < 20){
        float sf = snewF[m * 65 + dcol] + acc[reg] + b2[dcol];
        sfinF[m * 65 + dcol] = sf;
        slots[((size_t)b * 20 + m) * 64 + dcol] = sf;
        if (last) out_slots[((size_t)b * 20 + m) * 64 + dcol] = sf;
      }
    }
  }
  if (last) return;
  __syncthreads();

  // phase 5a: LN_slot(new slots) -> sqbf
  {
    const int d = lane;
    const float lg = lsg[d], lb = lsb[d];
    #pragma unroll
    for (int mi = 0; mi < 2; ++mi){
      int m = wv + mi * 16;
      if (m < 20){
        float sv = sfinF[m * 65 + d];
        float s1 = sv, s2 = sv * sv;
        #pragma unroll
        for (int off = 32; off >= 1; off >>= 1){
          s1 += __shfl_xor(s1, off);
          s2 += __shfl_xor(s2, off);
        }
        float mean = s1 * (1.f / 64.f);
        float var = s2 * (1.f / 64.f) - mean * mean;
        float rstd = rsqrtf(var + 1e-5f);
        float xn = (sv - mean) * rstd * lg + lb;
        *(unsigned short*)(sqbf + SWZ128(m * 128 + d * 2)) = f2bf(xn);
      }
    }
  }
  __syncthreads();
  // phase 5b: q = LNs @ Wq
  if (wv < 8){
    const int jt = wv >> 1, mg = wv & 1;
    f32x4 acc = (f32x4){0.f,0.f,0.f,0.f};
    #pragma unroll
    for (int kst = 0; kst < 2; ++kst){
      bf16x8 afrag = *(const bf16x8*)(PWq + ((size_t)((jt * 2 + kst) * 64 + lane)) * 8);
      int roff = (mg * 16 + l15) * 128 + (kst * 32 + g4 * 8) * 2;
      bf16x8 bfrag = *(const bf16x8*)(sqbf + SWZ128(roff));
      acc = __builtin_amdgcn_mfma_f32_16x16x32_bf16(afrag, bfrag, acc, 0, 0, 0);
    }
    #pragma unroll
    for (int reg = 0; reg < 4; ++reg){
      int m = mg * 16 + l15;
      int j = jt * 16 + g4 * 4 + reg;
      if (m < 20) qws[(size_t)b * 1280 + m * 64 + j] = acc[reg];
    }
  }
}

// ---------------------------------------------------------------------------
extern "C" void kernel_launch(void* const* d_in, const int* in_sizes, int n_in,
                              void* d_out, int out_size, void* d_ws, size_t ws_size,
                              hipStream_t stream){
  const float* inputs = (const float*)d_in[0];
  const float* noise  = (const float*)d_in[1];
  const float* mu     = (const float*)d_in[2];
  const float* lsig   = (const float*)d_in[3];
  const float* ln_in_g= (const float*)d_in[4];
  const float* ln_in_b= (const float*)d_in[5];
  const float* Wk     = (const float*)d_in[6];
  const float* Wv     = (const float*)d_in[7];
  const float* Wq     = (const float*)d_in[8];
  const float* ln_s_g = (const float*)d_in[9];
  const float* ln_s_b = (const float*)d_in[10];
  const float* Wih    = (const float*)d_in[11];
  const float* Whh    = (const float*)d_in[12];
  const float* bih    = (const float*)d_in[13];
  const float* bhh    = (const float*)d_in[14];
  const float* lmg    = (const float*)d_in[15];
  const float* lmb    = (const float*)d_in[16];
  const float* W1     = (const float*)d_in[17];
  const float* b1     = (const float*)d_in[18];
  const float* W2     = (const float*)d_in[19];
  const float* b2     = (const float*)d_in[20];

  char* ws = (char*)d_ws;
  unsigned short* kbF = (unsigned short*)ws;                  // 33,554,432 B
  unsigned short* vF  = (unsigned short*)(ws + 33554432);     // 33,554,432 B
  unsigned short* PWt = (unsigned short*)(ws + 67108864);     // 65,536 B
  float* slots        = (float*)(ws + 67174400);              // 327,680 B
  float* qws          = (float*)(ws + 67502080);              // 327,680 B
  float* Uacc         = (float*)(ws + 67829760);              // 327,680 B (+Sacc tail)
  float* Sacc         = (float*)(ws + 68157440);              // 5,120 B
  unsigned short* PWih= (unsigned short*)(ws + 68162560);     // 24,576 B
  unsigned short* PWhh= (unsigned short*)(ws + 68187136);     // 24,576 B
  unsigned short* PW1T= (unsigned short*)(ws + 68211712);     // 32,768 B
  unsigned short* PW2T= (unsigned short*)(ws + 68244480);     // 32,768 B
  unsigned short* PWq = (unsigned short*)(ws + 68277248);     // 8,192 B

  float* slots_out = (float*)d_out;
  float* attn_out  = slots_out + 81920;

  hipLaunchKernelGGL(k_prep, dim3(128), dim3(256), 0, stream, Wk, Wv, PWt, Uacc);
  hipLaunchKernelGGL(k_lnkv, dim3(8752), dim3(256), 20480, stream, inputs, ln_in_g, ln_in_b,
                     PWt, kbF, vF,
                     Wih, Whh, W1, W2, Wq, noise, mu, lsig, ln_s_g, ln_s_b,
                     PWih, PWhh, PW1T, PW2T, PWq, slots, qws);

  for (int it = 0; it < 3; ++it){
    hipLaunchKernelGGL(k_attn2, dim3(32, 64), dim3(256), 0, stream, kbF, vF, qws, Sacc, Uacc,
                       attn_out, (it == 2) ? 1 : 0);
    hipLaunchKernelGGL(k_slot, dim3(64), dim3(1024), 92160, stream, slots, Uacc, Sacc,
                       PWih, PWhh, PW1T, PW2T, PWq, bih, bhh, b1, b2,
                       lmg, lmb, ln_s_g, ln_s_b, qws, slots_out, (it == 2) ? 1 : 0);
  }
}

// Round 13
// 164.111 us; speedup vs baseline: 1.1270x; 1.1270x over previous
//
#include <hip/hip_runtime.h>
#include <cstdint>
#include <cstddef>

using f32x4  = __attribute__((ext_vector_type(4))) float;
using bf16x8 = __attribute__((ext_vector_type(8))) short;

__device__ __forceinline__ unsigned short f2bf(float f){
  unsigned int u = __float_as_uint(f);
  return (unsigned short)((u + 0x7fffu + ((u >> 16) & 1u)) >> 16);
}

// swizzles: XOR 16B-slot bits with row&7 (row = 512B or 128B)
#define SWZ(o)    ((o) ^ ((((o) >> 9) & 7) << 4))
#define SWZ128(o) ((o) ^ ((((o) >> 7) & 7) << 4))

// ---------------------------------------------------------------------------
// Prologue: PWt (k/v weights in MFMA B-frag order) + packed slot weights +
// slot init + initial q.
__global__ __launch_bounds__(256) void k_prep(
    const float* __restrict__ Wk, const float* __restrict__ Wv,
    const float* __restrict__ Wih, const float* __restrict__ Whh,
    const float* __restrict__ W1,  const float* __restrict__ W2,
    const float* __restrict__ Wq,
    const float* __restrict__ noise, const float* __restrict__ mu,
    const float* __restrict__ lsig,
    const float* __restrict__ lsg, const float* __restrict__ lsb,
    unsigned short* __restrict__ PWt,
    unsigned short* __restrict__ PWih, unsigned short* __restrict__ PWhh,
    unsigned short* __restrict__ PW1T, unsigned short* __restrict__ PW2T,
    unsigned short* __restrict__ PWq,
    float* __restrict__ slots, float* __restrict__ qws){
  const int bx = blockIdx.x, t = threadIdx.x;
  if (bx < 128){
    int idx = bx * 256 + t;                   // 32768 total
    int e = idx & 7, lane = (idx >> 3) & 63, f = idx >> 9;
    int pass = f >> 5, brT = (f >> 3) & 3, kk = f & 7;
    int n_loc = brT * 16 + (lane & 15);
    int c = kk * 32 + (lane >> 4) * 8 + e;
    const float* src = pass ? Wv : Wk;
    PWt[idx] = f2bf(src[c * 64 + n_loc]);
    return;
  }
  if (bx < 368){
    int idx = (bx - 128) * 256 + t;   // 61440 total
    int rel, kstN;
    const float* src; unsigned short* dst; int mode;
    if (idx < 12288)      { rel = idx;          kstN = 2; src = Wih; dst = PWih; mode = 0; }
    else if (idx < 24576) { rel = idx - 12288;  kstN = 2; src = Whh; dst = PWhh; mode = 0; }
    else if (idx < 40960) { rel = idx - 24576;  kstN = 2; src = W1;  dst = PW1T; mode = 1; }
    else if (idx < 57344) { rel = idx - 40960;  kstN = 8; src = W2;  dst = PW2T; mode = 2; }
    else                  { rel = idx - 57344;  kstN = 2; src = Wq;  dst = PWq;  mode = 3; }
    int e = rel & 7, lane = (rel >> 3) & 63, f = rel >> 9;
    int jt = f / kstN, kst = f - jt * kstN;
    int row = jt * 16 + (lane & 15);
    int col = kst * 32 + (lane >> 4) * 8 + e;
    float v;
    if (mode == 0)      v = src[row * 64 + col];
    else if (mode == 1) v = src[col * 256 + row];
    else if (mode == 2) v = src[col * 64 + row];
    else                v = src[col * 64 + row];
    dst[rel] = f2bf(v);
    return;
  }
  {
    __shared__ __align__(16) float xsh[4][64];
    int idx = bx - 368;
    int d = t & 63, w4 = t >> 6;
    int bk = idx * 4 + w4;
    float s = mu[d] + __expf(lsig[d]) * noise[bk * 64 + d];
    slots[bk * 64 + d] = s;
    float s1 = s, s2 = s * s;
    #pragma unroll
    for (int off = 32; off >= 1; off >>= 1){
      s1 += __shfl_xor(s1, off);
      s2 += __shfl_xor(s2, off);
    }
    float m = s1 * (1.f / 64.f);
    float var = s2 * (1.f / 64.f) - m * m;
    float rstd = rsqrtf(var + 1e-5f);
    float xn = (s - m) * rstd * lsg[d] + lsb[d];
    xsh[w4][d] = xn;
    __syncthreads();
    float q = 0.f;
    #pragma unroll
    for (int i = 0; i < 64; ++i) q += xsh[w4][i] * Wq[i * 64 + d];
    qws[bk * 64 + d] = q;
  }
}

// ---------------------------------------------------------------------------
// Fused LN + (x@Wk | x@Wv), BM=32 (8 blocks/CU for 2x memory parallelism).
// Outputs in MFMA B-fragment order (kbF for QK^T, vF for PV).
__global__ __launch_bounds__(256) void k_lnkv(
    const float* __restrict__ x, const float* __restrict__ lng, const float* __restrict__ lnb,
    const unsigned short* __restrict__ PWt,
    unsigned short* __restrict__ kbF, unsigned short* __restrict__ vF){
  extern __shared__ char smem[];
  char* As = smem;            // 32 x 256 bf16, swizzled (16KB)
  char* Cs = smem + 16384;    // 32 x 64 bf16 output staging (4KB)
  const int t = threadIdx.x;
  const int lane = t & 63, w = t >> 6;
  const int gm0 = blockIdx.x * 32;

  const float4 g4 = *(const float4*)(lng + lane * 4);
  const float4 b4 = *(const float4*)(lnb + lane * 4);

  // phase A: wave w handles rows w*8 .. w*8+7
  {
    float4 xv[8];
    #pragma unroll
    for (int j = 0; j < 8; ++j){
      int r = w * 8 + j;
      xv[j] = *(const float4*)(x + (size_t)(gm0 + r) * 256 + lane * 4);
    }
    #pragma unroll
    for (int j = 0; j < 8; ++j){
      int r = w * 8 + j;
      float4 v = xv[j];
      float s  = v.x + v.y + v.z + v.w;
      float s2 = v.x * v.x + v.y * v.y + v.z * v.z + v.w * v.w;
      #pragma unroll
      for (int off = 32; off >= 1; off >>= 1){
        s  += __shfl_xor(s,  off);
        s2 += __shfl_xor(s2, off);
      }
      float mean = s * (1.f / 256.f);
      float var  = s2 * (1.f / 256.f) - mean * mean;
      float rstd = rsqrtf(var + 1e-5f);
      unsigned int p0 = (unsigned)f2bf((v.x - mean) * rstd * g4.x + b4.x) |
                        ((unsigned)f2bf((v.y - mean) * rstd * g4.y + b4.y) << 16);
      unsigned int p1 = (unsigned)f2bf((v.z - mean) * rstd * g4.z + b4.z) |
                        ((unsigned)f2bf((v.w - mean) * rstd * g4.w + b4.w) << 16);
      int off8 = r * 512 + lane * 8;
      *(uint2*)(As + SWZ(off8)) = make_uint2(p0, p1);
    }
  }
  __syncthreads();

  const int wm = w >> 1, wn = w & 1;        // wm: row-tile(16) of 32; wn: col-half of 64
  const int l15 = lane & 15, l4 = lane >> 4;

  #pragma unroll 1
  for (int pass = 0; pass < 2; ++pass){
    f32x4 acc[2];
    acc[0] = (f32x4){0.f,0.f,0.f,0.f};
    acc[1] = (f32x4){0.f,0.f,0.f,0.f};

    #pragma unroll
    for (int kk = 0; kk < 8; ++kk){
      int ar = wm * 16 + l15;
      bf16x8 a = *(const bf16x8*)(As + SWZ(ar * 512 + kk * 64 + l4 * 16));
      bf16x8 bfr[2];
      #pragma unroll
      for (int j = 0; j < 2; ++j){
        int f = pass * 32 + (wn * 2 + j) * 8 + kk;
        bfr[j] = *(const bf16x8*)(PWt + ((size_t)(f * 64 + lane)) * 8);
      }
      #pragma unroll
      for (int j = 0; j < 2; ++j)
        acc[j] = __builtin_amdgcn_mfma_f32_16x16x32_bf16(a, bfr[j], acc[j], 0, 0, 0);
    }
    if (pass == 1) __syncthreads();   // pass0's Cs reads complete before overwrite

    #pragma unroll
    for (int j = 0; j < 2; ++j)
      #pragma unroll
      for (int reg = 0; reg < 4; ++reg){
        int row = wm * 16 + l4 * 4 + reg;
        int colb = ((wn * 2 + j) * 16 + l15) * 2;
        *(unsigned short*)(Cs + row * 128 + (colb ^ ((row & 7) << 4))) = f2bf(acc[j][reg]);
      }
    __syncthreads();

    if (pass == 0){
      // k -> QK^T B-frag: lane_out lo, kst, nt: val = Cs[nt*16+(lo&15)][kst*32+(lo>>4)*8+e]
      const int lo = t & 63, kst = (t >> 6) & 1, nt = t >> 7;
      int row = nt * 16 + (lo & 15);
      int colb = (kst * 32 + (lo >> 4) * 8) * 2;
      uint4 val = *(const uint4*)(Cs + row * 128 + (colb ^ ((row & 7) << 4)));
      size_t ntile = (size_t)blockIdx.x * 2 + nt;
      *(uint4*)(kbF + (ntile * 2 + kst) * 512 + lo * 8) = val;
    } else {
      // v -> PV B-frag: block covers one 32-row kst group of its 128-n chunk
      const size_t chunkF = (size_t)(gm0 >> 7);
      const int kstG = (gm0 >> 5) & 3;
      const int dtile = t >> 6;
      unsigned short ev[8];
      #pragma unroll
      for (int e = 0; e < 8; ++e){
        int row = (lane >> 4) * 8 + e;
        int colb = (dtile * 16 + (lane & 15)) * 2;
        ev[e] = *(const unsigned short*)(Cs + row * 128 + (colb ^ ((row & 7) << 4)));
      }
      *(uint4*)(vF + ((chunkF * 4 + dtile) * 4 + kstG) * 512 + lane * 8) = *(const uint4*)ev;
    }
  }
}

// ---------------------------------------------------------------------------
// MFMA attention, fragment-direct.
__global__ __launch_bounds__(256) void k_attn2(
    const unsigned short* __restrict__ kbF, const unsigned short* __restrict__ vF,
    const float* __restrict__ qws, float* __restrict__ Spart, float* __restrict__ Upart,
    float* __restrict__ attn_out, int write_attn){
  __shared__ __align__(16) char sm[12672];
  char* qs  = sm;                       // [32][64] bf16 swz (4KB)
  char* Ps  = sm + 4096;                // [32][128] bf16 swz (8KB)
  float* sred = (float*)(sm + 12288);   // [20][4]
  const int t = threadIdx.x, lane = t & 63, w = t >> 6;
  const int l15 = lane & 15, g = lane >> 4;
  const int b = blockIdx.y, chunk = blockIdx.x, n0 = chunk * 128;

  if (t < 160){
    int r = t >> 3, c = t & 7;
    const float4* qp = (const float4*)(qws + (size_t)b * 1280 + r * 64 + c * 8);
    float4 a0 = qp[0], a1 = qp[1];
    uint4 pk;
    pk.x = (unsigned)f2bf(a0.x) | ((unsigned)f2bf(a0.y) << 16);
    pk.y = (unsigned)f2bf(a0.z) | ((unsigned)f2bf(a0.w) << 16);
    pk.z = (unsigned)f2bf(a1.x) | ((unsigned)f2bf(a1.y) << 16);
    pk.w = (unsigned)f2bf(a1.z) | ((unsigned)f2bf(a1.w) << 16);
    *(uint4*)(qs + r * 128 + ((c * 16) ^ ((r & 7) << 4))) = pk;
  }
  __syncthreads();

  f32x4 c2[2][2];
  #pragma unroll
  for (int kt = 0; kt < 2; ++kt)
    #pragma unroll
    for (int nt = 0; nt < 2; ++nt)
      c2[kt][nt] = (f32x4){0.f, 0.f, 0.f, 0.f};
  #pragma unroll
  for (int kst = 0; kst < 2; ++kst){
    bf16x8 aq[2], bk2[2];
    #pragma unroll
    for (int kt = 0; kt < 2; ++kt){
      int row = kt * 16 + l15;
      aq[kt] = *(const bf16x8*)(qs + row * 128 + ((kst * 64 + g * 16) ^ ((row & 7) << 4)));
    }
    #pragma unroll
    for (int nt = 0; nt < 2; ++nt){
      size_t ntile = (size_t)b * 256 + chunk * 8 + w * 2 + nt;
      bk2[nt] = *(const bf16x8*)(kbF + (ntile * 2 + kst) * 512 + lane * 8);
    }
    #pragma unroll
    for (int kt = 0; kt < 2; ++kt)
      #pragma unroll
      for (int nt = 0; nt < 2; ++nt)
        c2[kt][nt] = __builtin_amdgcn_mfma_f32_16x16x32_bf16(aq[kt], bk2[nt], c2[kt][nt], 0, 0, 0);
  }

  float p[2][2][4];
  #pragma unroll
  for (int kt = 0; kt < 2; ++kt)
    #pragma unroll
    for (int nt = 0; nt < 2; ++nt)
      #pragma unroll
      for (int reg = 0; reg < 4; ++reg)
        p[kt][nt][reg] = c2[kt][nt][reg] * 0.125f;
  if (g){
    #pragma unroll
    for (int nt = 0; nt < 2; ++nt)
      #pragma unroll
      for (int reg = 0; reg < 4; ++reg)
        p[1][nt][reg] = -1e30f;
  }

  #pragma unroll
  for (int nt = 0; nt < 2; ++nt){
    float mx = p[0][nt][0];
    #pragma unroll
    for (int reg = 1; reg < 4; ++reg) mx = fmaxf(mx, p[0][nt][reg]);
    #pragma unroll
    for (int reg = 0; reg < 4; ++reg) mx = fmaxf(mx, p[1][nt][reg]);
    mx = fmaxf(mx, __shfl_xor(mx, 16));
    mx = fmaxf(mx, __shfl_xor(mx, 32));
    float s = 0.f;
    #pragma unroll
    for (int kt = 0; kt < 2; ++kt)
      #pragma unroll
      for (int reg = 0; reg < 4; ++reg){
        float e = __expf(p[kt][nt][reg] - mx);
        p[kt][nt][reg] = e; s += e;
      }
    s += __shfl_xor(s, 16);
    s += __shfl_xor(s, 32);
    float inv = 1.f / s;
    #pragma unroll
    for (int kt = 0; kt < 2; ++kt)
      #pragma unroll
      for (int reg = 0; reg < 4; ++reg)
        p[kt][nt][reg] *= inv;
  }

  {
    float sr[2][4];
    #pragma unroll
    for (int kt = 0; kt < 2; ++kt)
      #pragma unroll
      for (int reg = 0; reg < 4; ++reg)
        sr[kt][reg] = p[kt][0][reg] + p[kt][1][reg];
    #pragma unroll
    for (int off = 1; off <= 8; off <<= 1)
      #pragma unroll
      for (int kt = 0; kt < 2; ++kt)
        #pragma unroll
        for (int reg = 0; reg < 4; ++reg)
          sr[kt][reg] += __shfl_xor(sr[kt][reg], off);
    if (l15 == 0){
      #pragma unroll
      for (int kt = 0; kt < 2; ++kt)
        #pragma unroll
        for (int reg = 0; reg < 4; ++reg){
          int ks = kt * 16 + g * 4 + reg;
          if (ks < 20) sred[ks * 4 + w] = sr[kt][reg];
        }
    }
  }

  if (write_attn){
    #pragma unroll
    for (int kt = 0; kt < 2; ++kt)
      #pragma unroll
      for (int nt = 0; nt < 2; ++nt)
        #pragma unroll
        for (int reg = 0; reg < 4; ++reg){
          int ks = kt * 16 + g * 4 + reg;
          if (ks < 20)
            attn_out[((size_t)(b * 20 + ks)) * 4096 + n0 + w * 32 + nt * 16 + l15] = p[kt][nt][reg];
        }
  }

  #pragma unroll
  for (int kt = 0; kt < 2; ++kt)
    #pragma unroll
    for (int nt = 0; nt < 2; ++nt)
      #pragma unroll
      for (int reg = 0; reg < 4; ++reg){
        int row = kt * 16 + g * 4 + reg;
        int colb = (w * 32 + nt * 16 + l15) * 2;
        *(unsigned short*)(Ps + row * 256 + (colb ^ ((row & 7) << 4))) = f2bf(p[kt][nt][reg]);
      }
  __syncthreads();

  if (t < 20)
    Spart[((size_t)b * 20 + t) * 32 + chunk] =
        sred[t * 4 + 0] + sred[t * 4 + 1] + sred[t * 4 + 2] + sred[t * 4 + 3];

  f32x4 u[2];
  u[0] = (f32x4){0.f,0.f,0.f,0.f};
  u[1] = (f32x4){0.f,0.f,0.f,0.f};
  #pragma unroll
  for (int kst = 0; kst < 4; ++kst){
    bf16x8 pa[2], bv;
    #pragma unroll
    for (int kt = 0; kt < 2; ++kt){
      int row = kt * 16 + l15;
      pa[kt] = *(const bf16x8*)(Ps + row * 256 + ((kst * 64 + g * 16) ^ ((row & 7) << 4)));
    }
    bv = *(const bf16x8*)(vF + ((((size_t)b * 32 + chunk) * 4 + w) * 4 + kst) * 512 + lane * 8);
    #pragma unroll
    for (int kt = 0; kt < 2; ++kt)
      u[kt] = __builtin_amdgcn_mfma_f32_16x16x32_bf16(pa[kt], bv, u[kt], 0, 0, 0);
  }
  #pragma unroll
  for (int kt = 0; kt < 2; ++kt)
    #pragma unroll
    for (int reg = 0; reg < 4; ++reg){
      int ks = kt * 16 + g * 4 + reg;
      if (ks < 20)
        Upart[((size_t)(b * 32 + chunk) * 20 + ks) * 64 + w * 16 + l15] = u[kt][reg];
    }
}

// ---------------------------------------------------------------------------
// Fused slot update, 1024 threads (16 waves).
__global__ __launch_bounds__(1024) void k_slot(
    float* __restrict__ slots, const float* __restrict__ Upart, const float* __restrict__ Spart,
    const unsigned short* __restrict__ PWih, const unsigned short* __restrict__ PWhh,
    const unsigned short* __restrict__ PW1T, const unsigned short* __restrict__ PW2T,
    const unsigned short* __restrict__ PWq,
    const float* __restrict__ bih, const float* __restrict__ bhh,
    const float* __restrict__ b1, const float* __restrict__ b2,
    const float* __restrict__ lmg, const float* __restrict__ lmb,
    const float* __restrict__ lsg, const float* __restrict__ lsb,
    float* __restrict__ qws, float* __restrict__ out_slots, int last){
  extern __shared__ char sm[];
  float* g1f = (float*)sm;                 // [192][33] f32 (25,344B)
  float* g2f = g1f + 192 * 33;             // [192][33] f32
  char*  reluT = sm;                       // [32][256] bf16 swz512 (16KB) -- aliases g1f/g2f
  char*  ubf   = sm + 50688;               // [32][64] bf16 swz128 (4KB)
  char*  sbfb  = sm + 54784;
  char*  hbf   = sm + 58880;
  char*  sqbf  = sm + 62976;
  float* snewF = (float*)(sm + 67072);     // [32][65] f32
  float* prevF = (float*)(sm + 75392);
  float* sfinF = (float*)(sm + 83712);
  float* sSr   = (float*)(sm + 92032);     // [20] f32  (total 92,160B)

  const int t = threadIdx.x, lane = t & 63, wv = t >> 6;
  const int l15 = lane & 15, g4 = lane >> 4;
  const int b = blockIdx.x;

  // phase 0a: S reduce
  if (t < 20){
    const float* sp = Spart + ((size_t)b * 20 + t) * 32;
    float ss = 0.f;
    #pragma unroll
    for (int c = 0; c < 32; ++c) ss += sp[c];
    sSr[t] = 1.f / (ss + 1e-8f);
  }
  __syncthreads();

  // phase 0b: U reduce + stage updates/prev
  #pragma unroll
  for (int i = 0; i < 2; ++i){
    int idx = t + 1024 * i;
    if (idx < 1280){
      int m = idx >> 6, d = idx & 63;
      const float* up = Upart + (size_t)b * 40960 + m * 64 + d;
      float uv = 0.f;
      #pragma unroll
      for (int c = 0; c < 32; ++c) uv += up[(size_t)c * 1280];
      uv *= sSr[m];
      float pv = slots[((size_t)b * 20 + m) * 64 + d];
      int off = m * 128 + d * 2;
      *(unsigned short*)(ubf  + SWZ128(off)) = f2bf(uv);
      *(unsigned short*)(sbfb + SWZ128(off)) = f2bf(pv);
      prevF[m * 65 + d] = pv;
    }
  }
  __syncthreads();

  // phase 1: gate GEMMs. wave role: which = wv>>3, mg = (wv>>2)&1, jg = wv&3 (3 jt each)
  {
    const int which = wv >> 3, mg = (wv >> 2) & 1, jg = wv & 3;
    const unsigned short* PA = which ? PWhh : PWih;
    const char* Bt = which ? sbfb : ubf;
    float* gout = which ? g2f : g1f;
    f32x4 acc[3];
    #pragma unroll
    for (int jj = 0; jj < 3; ++jj) acc[jj] = (f32x4){0.f,0.f,0.f,0.f};
    #pragma unroll
    for (int kst = 0; kst < 2; ++kst){
      int roff = (mg * 16 + l15) * 128 + (kst * 32 + g4 * 8) * 2;
      bf16x8 bfrag = *(const bf16x8*)(Bt + SWZ128(roff));
      #pragma unroll
      for (int jj = 0; jj < 3; ++jj){
        int jt = jg * 3 + jj;
        bf16x8 afrag = *(const bf16x8*)(PA + ((size_t)((jt * 2 + kst) * 64 + lane)) * 8);
        acc[jj] = __builtin_amdgcn_mfma_f32_16x16x32_bf16(afrag, bfrag, acc[jj], 0, 0, 0);
      }
    }
    #pragma unroll
    for (int jj = 0; jj < 3; ++jj){
      int jt = jg * 3 + jj;
      #pragma unroll
      for (int reg = 0; reg < 4; ++reg)
        gout[(jt * 16 + g4 * 4 + reg) * 33 + mg * 16 + l15] = acc[jj][reg];
    }
  }
  __syncthreads();

  // phase 2: gate combine + GRU + LN(mlp) -> hbf ; wave wv handles m = wv, 16+wv
  {
    const int d = lane;
    const float bi_r = bih[d], bi_z = bih[64 + d], bi_n = bih[128 + d];
    const float bh_r = bhh[d], bh_z = bhh[64 + d], bh_n = bhh[128 + d];
    const float lg = lmg[d], lb = lmb[d];
    #pragma unroll
    for (int mi = 0; mi < 2; ++mi){
      int m = wv + mi * 16;
      if (m < 20){
        float i_r = g1f[d * 33 + m] + bi_r;
        float i_z = g1f[(64 + d) * 33 + m] + bi_z;
        float i_n = g1f[(128 + d) * 33 + m] + bi_n;
        float h_r = g2f[d * 33 + m] + bh_r;
        float h_z = g2f[(64 + d) * 33 + m] + bh_z;
        float h_n = g2f[(128 + d) * 33 + m] + bh_n;
        float r = 1.f / (1.f + __expf(-(i_r + h_r)));
        float z = 1.f / (1.f + __expf(-(i_z + h_z)));
        float nn = tanhf(i_n + r * h_n);
        float pv = prevF[m * 65 + d];
        float sn = (1.f - z) * nn + z * pv;
        snewF[m * 65 + d] = sn;
        float s1 = sn, s2 = sn * sn;
        #pragma unroll
        for (int off = 32; off >= 1; off >>= 1){
          s1 += __shfl_xor(s1, off);
          s2 += __shfl_xor(s2, off);
        }
        float mean = s1 * (1.f / 64.f);
        float var = s2 * (1.f / 64.f) - mean * mean;
        float rstd = rsqrtf(var + 1e-5f);
        float h = (sn - mean) * rstd * lg + lb;
        *(unsigned short*)(hbf + SWZ128(m * 128 + d * 2)) = f2bf(h);
      }
    }
  }
  __syncthreads();

  // phase 3: relu(h@W1+b1) -> reluT ; wave wv owns jt = wv (both mg)
  {
    const int jt = wv;
    f32x4 acc[2];
    acc[0] = (f32x4){0.f,0.f,0.f,0.f};
    acc[1] = (f32x4){0.f,0.f,0.f,0.f};
    #pragma unroll
    for (int kst = 0; kst < 2; ++kst){
      bf16x8 afrag = *(const bf16x8*)(PW1T + ((size_t)((jt * 2 + kst) * 64 + lane)) * 8);
      #pragma unroll
      for (int mg = 0; mg < 2; ++mg){
        int roff = (mg * 16 + l15) * 128 + (kst * 32 + g4 * 8) * 2;
        bf16x8 bh2 = *(const bf16x8*)(hbf + SWZ128(roff));
        acc[mg] = __builtin_amdgcn_mfma_f32_16x16x32_bf16(afrag, bh2, acc[mg], 0, 0, 0);
      }
    }
    #pragma unroll
    for (int reg = 0; reg < 4; ++reg){
      int j = jt * 16 + g4 * 4 + reg;
      float bb = b1[j];
      #pragma unroll
      for (int mg = 0; mg < 2; ++mg){
        float vv = fmaxf(acc[mg][reg] + bb, 0.f);
        int m = mg * 16 + l15;
        int off = m * 512 + j * 2;
        *(unsigned short*)(reluT + SWZ(off)) = f2bf(vv);
      }
    }
  }
  __syncthreads();

  // phase 4: relu@W2 + b2 + snew -> slots ; waves 0..7: dd = wv>>1, mg = wv&1
  if (wv < 8){
    const int dd = wv >> 1, mg = wv & 1;
    f32x4 acc = (f32x4){0.f,0.f,0.f,0.f};
    #pragma unroll
    for (int kst = 0; kst < 8; ++kst){
      bf16x8 afrag = *(const bf16x8*)(PW2T + ((size_t)((dd * 8 + kst) * 64 + lane)) * 8);
      int row = mg * 16 + l15;
      int off = row * 512 + (kst * 32 + g4 * 8) * 2;
      bf16x8 bfrag = *(const bf16x8*)(reluT + SWZ(off));
      acc = __builtin_amdgcn_mfma_f32_16x16x32_bf16(afrag, bfrag, acc, 0, 0, 0);
    }
    #pragma unroll
    for (int reg = 0; reg < 4; ++reg){
      int m = mg * 16 + l15;
      int dcol = dd * 16 + g4 * 4 + reg;
      if (m < 20){
        float sf = snewF[m * 65 + dcol] + acc[reg] + b2[dcol];
        sfinF[m * 65 + dcol] = sf;
        slots[((size_t)b * 20 + m) * 64 + dcol] = sf;
        if (last) out_slots[((size_t)b * 20 + m) * 64 + dcol] = sf;
      }
    }
  }
  if (last) return;
  __syncthreads();

  // phase 5a: LN_slot(new slots) -> sqbf ; wave wv handles m = wv, 16+wv
  {
    const int d = lane;
    const float lg = lsg[d], lb = lsb[d];
    #pragma unroll
    for (int mi = 0; mi < 2; ++mi){
      int m = wv + mi * 16;
      if (m < 20){
        float sv = sfinF[m * 65 + d];
        float s1 = sv, s2 = sv * sv;
        #pragma unroll
        for (int off = 32; off >= 1; off >>= 1){
          s1 += __shfl_xor(s1, off);
          s2 += __shfl_xor(s2, off);
        }
        float mean = s1 * (1.f / 64.f);
        float var = s2 * (1.f / 64.f) - mean * mean;
        float rstd = rsqrtf(var + 1e-5f);
        float xn = (sv - mean) * rstd * lg + lb;
        *(unsigned short*)(sqbf + SWZ128(m * 128 + d * 2)) = f2bf(xn);
      }
    }
  }
  __syncthreads();
  // phase 5b: q = LNs @ Wq ; waves 0..7: jt = wv>>1, mg = wv&1
  if (wv < 8){
    const int jt = wv >> 1, mg = wv & 1;
    f32x4 acc = (f32x4){0.f,0.f,0.f,0.f};
    #pragma unroll
    for (int kst = 0; kst < 2; ++kst){
      bf16x8 afrag = *(const bf16x8*)(PWq + ((size_t)((jt * 2 + kst) * 64 + lane)) * 8);
      int roff = (mg * 16 + l15) * 128 + (kst * 32 + g4 * 8) * 2;
      bf16x8 bfrag = *(const bf16x8*)(sqbf + SWZ128(roff));
      acc = __builtin_amdgcn_mfma_f32_16x16x32_bf16(afrag, bfrag, acc, 0, 0, 0);
    }
    #pragma unroll
    for (int reg = 0; reg < 4; ++reg){
      int m = mg * 16 + l15;
      int j = jt * 16 + g4 * 4 + reg;
      if (m < 20) qws[(size_t)b * 1280 + m * 64 + j] = acc[reg];
    }
  }
}

// ---------------------------------------------------------------------------
extern "C" void kernel_launch(void* const* d_in, const int* in_sizes, int n_in,
                              void* d_out, int out_size, void* d_ws, size_t ws_size,
                              hipStream_t stream){
  const float* inputs = (const float*)d_in[0];
  const float* noise  = (const float*)d_in[1];
  const float* mu     = (const float*)d_in[2];
  const float* lsig   = (const float*)d_in[3];
  const float* ln_in_g= (const float*)d_in[4];
  const float* ln_in_b= (const float*)d_in[5];
  const float* Wk     = (const float*)d_in[6];
  const float* Wv     = (const float*)d_in[7];
  const float* Wq     = (const float*)d_in[8];
  const float* ln_s_g = (const float*)d_in[9];
  const float* ln_s_b = (const float*)d_in[10];
  const float* Wih    = (const float*)d_in[11];
  const float* Whh    = (const float*)d_in[12];
  const float* bih    = (const float*)d_in[13];
  const float* bhh    = (const float*)d_in[14];
  const float* lmg    = (const float*)d_in[15];
  const float* lmb    = (const float*)d_in[16];
  const float* W1     = (const float*)d_in[17];
  const float* b1     = (const float*)d_in[18];
  const float* W2     = (const float*)d_in[19];
  const float* b2     = (const float*)d_in[20];

  char* ws = (char*)d_ws;
  unsigned short* kbF = (unsigned short*)ws;                  // 33,554,432 B
  unsigned short* vF  = (unsigned short*)(ws + 33554432);     // 33,554,432 B
  unsigned short* PWt = (unsigned short*)(ws + 67108864);     // 65,536 B
  float* slots        = (float*)(ws + 67174400);              // 327,680 B
  float* qws          = (float*)(ws + 67502080);              // 327,680 B
  float* Upart        = (float*)(ws + 67829760);              // 10,485,760 B
  float* Spart        = (float*)(ws + 78315520);              // 163,840 B
  unsigned short* PWih= (unsigned short*)(ws + 78479360);     // 24,576 B
  unsigned short* PWhh= (unsigned short*)(ws + 78503936);     // 24,576 B
  unsigned short* PW1T= (unsigned short*)(ws + 78528512);     // 32,768 B
  unsigned short* PW2T= (unsigned short*)(ws + 78561280);     // 32,768 B
  unsigned short* PWq = (unsigned short*)(ws + 78594048);     // 8,192 B

  float* slots_out = (float*)d_out;
  float* attn_out  = slots_out + 81920;

  hipLaunchKernelGGL(k_prep, dim3(688), dim3(256), 0, stream,
                     Wk, Wv, Wih, Whh, W1, W2, Wq, noise, mu, lsig, ln_s_g, ln_s_b,
                     PWt, PWih, PWhh, PW1T, PW2T, PWq, slots, qws);
  hipLaunchKernelGGL(k_lnkv, dim3(8192), dim3(256), 20480, stream, inputs, ln_in_g, ln_in_b,
                     PWt, kbF, vF);

  for (int it = 0; it < 3; ++it){
    hipLaunchKernelGGL(k_attn2, dim3(32, 64), dim3(256), 0, stream, kbF, vF, qws, Spart, Upart,
                       attn_out, (it == 2) ? 1 : 0);
    hipLaunchKernelGGL(k_slot, dim3(64), dim3(1024), 92160, stream, slots, Upart, Spart,
                       PWih, PWhh, PW1T, PW2T, PWq, bih, bhh, b1, b2,
                       lmg, lmb, ln_s_g, ln_s_b, qws, slots_out, (it == 2) ? 1 : 0);
  }
}